// Round 5
// baseline (350.698 us; speedup 1.0000x reference)
//
#include <hip/hip_runtime.h>
#include <cstdint>
#include <cstddef>

#define NN 100000
#define NE 1600000
#define IND 500
#define HD 64
#define OD 40
#define NBLK ((NN + 255) / 256)   // 391 scan blocks
#define KSTEPS 16                 // ceil(500/32)

typedef __attribute__((ext_vector_type(8))) short short8v;
typedef __attribute__((ext_vector_type(8))) __bf16 bf16x8;
typedef __attribute__((ext_vector_type(4))) float float4v;

// MFMA builtin signature differs across toolchains (short8 vs bf16x8).
template <class V>
static __device__ __forceinline__ auto mfma_bf16_(V a, V b, float4v c, int)
    -> decltype(__builtin_amdgcn_mfma_f32_16x16x32_bf16(a, b, c, 0, 0, 0)) {
    return __builtin_amdgcn_mfma_f32_16x16x32_bf16(a, b, c, 0, 0, 0);
}
template <class V>
static __device__ __forceinline__ float4v mfma_bf16_(V a, V b, float4v c, long) {
    return __builtin_amdgcn_mfma_f32_16x16x32_bf16((bf16x8)a, (bf16x8)b, c, 0, 0, 0);
}
static __device__ __forceinline__ float4v mfma16(short8v a, short8v b, float4v c) {
    return mfma_bf16_(a, b, c, 0);
}

static __device__ __forceinline__ float bf2f(unsigned short v) {
    return __uint_as_float((unsigned)v << 16);
}
static __device__ __forceinline__ unsigned short f2bf(float v) {
    unsigned u = __float_as_uint(v);
    return (unsigned short)((u + 0x7fffu + ((u >> 16) & 1u)) >> 16);
}

// ---------- edge loading (int32 vs int64 auto-detect) ----------
__global__ void k_detect(const unsigned* ei32, int* flags) {
    if (threadIdx.x == 0 && blockIdx.x == 0) {
        int is64 = 1;
        #pragma unroll
        for (int i = 1; i < 16; i += 2)
            if (ei32[i] != 0u) is64 = 0;
        flags[0] = is64;
    }
}

// load 4 consecutive edge entries starting at element index base (base % 4 == 0)
static __device__ __forceinline__ void load4e(const void* ei, int is64, size_t base, int v[4]) {
    if (is64) {
        int4 a = ((const int4*)ei)[base >> 1];
        int4 b = ((const int4*)ei)[(base >> 1) + 1];
        v[0] = a.x; v[1] = a.z; v[2] = b.x; v[3] = b.z;
    } else {
        int4 a = *(const int4*)((const int*)ei + base);
        v[0] = a.x; v[1] = a.y; v[2] = a.z; v[3] = a.w;
    }
}

// ---------- degree histogram + per-edge rank (atomic return value) ----------
__global__ void k_count(const void* ei, const int* __restrict__ flags, int* cnt,
                        int* __restrict__ rank) {
    int e0 = (blockIdx.x * 256 + threadIdx.x) * 4;
    if (e0 >= NE) return;
    int d[4];
    load4e(ei, flags[0], (size_t)NE + e0, d);
    int4 r;
    r.x = atomicAdd(&cnt[d[0]], 1);
    r.y = atomicAdd(&cnt[d[1]], 1);
    r.z = atomicAdd(&cnt[d[2]], 1);
    r.w = atomicAdd(&cnt[d[3]], 1);
    *(int4*)(rank + e0) = r;
}

// ---------- exclusive scan (3 kernels); dinv fused into pass 1 ----------
__global__ __launch_bounds__(256) void k_scan_block(const int* __restrict__ cnt,
                                                    int* __restrict__ rowptr,
                                                    int* __restrict__ bsum,
                                                    float* __restrict__ dinv) {
    int t = threadIdx.x;
    int i = blockIdx.x * 256 + t;
    int v = (i < NN) ? cnt[i] : 0;
    if (i < NN) dinv[i] = rsqrtf((float)v + 1.0f);   // +1 = self loop
    int inc = v;
    #pragma unroll
    for (int off = 1; off < 64; off <<= 1) {
        int u = __shfl_up(inc, off);
        if ((t & 63) >= off) inc += u;
    }
    __shared__ int wsum[4];
    if ((t & 63) == 63) wsum[t >> 6] = inc;
    __syncthreads();
    if (t == 0) {
        int a = 0;
        #pragma unroll
        for (int w = 0; w < 4; ++w) { int b = wsum[w]; wsum[w] = a; a += b; }
        bsum[blockIdx.x] = a;
    }
    __syncthreads();
    if (i < NN) rowptr[i] = inc - v + wsum[t >> 6];
}

__global__ __launch_bounds__(512) void k_scan_bsum(int* bsum) {
    int t = threadIdx.x;
    int v = (t < NBLK) ? bsum[t] : 0;
    int inc = v;
    #pragma unroll
    for (int off = 1; off < 64; off <<= 1) {
        int u = __shfl_up(inc, off);
        if ((t & 63) >= off) inc += u;
    }
    __shared__ int wsum[8];
    if ((t & 63) == 63) wsum[t >> 6] = inc;
    __syncthreads();
    if (t == 0) {
        int a = 0;
        #pragma unroll
        for (int w = 0; w < 8; ++w) { int b = wsum[w]; wsum[w] = a; a += b; }
    }
    __syncthreads();
    if (t < NBLK) bsum[t] = inc - v + wsum[t >> 6];
}

__global__ void k_scan_add(int* rowptr, const int* __restrict__ bsum) {
    int i = blockIdx.x * 256 + threadIdx.x;
    if (i < NN) rowptr[i] += bsum[i >> 8];
    if (i == 0) rowptr[NN] = NE;
}

// ---------- counting-sort scatter (no atomics: pos = rowptr[d] + rank[e]) ----------
__global__ void k_scatter(const void* ei, const int* __restrict__ flags,
                          const int* __restrict__ rowptr, const int* __restrict__ rank,
                          int* __restrict__ srcs) {
    int e0 = (blockIdx.x * 256 + threadIdx.x) * 4;
    if (e0 >= NE) return;
    int is64 = flags[0];
    int s[4], d[4];
    load4e(ei, is64, (size_t)e0, s);
    load4e(ei, is64, (size_t)NE + e0, d);
    int4 r = *(const int4*)(rank + e0);
    int p0 = rowptr[d[0]] + r.x;
    int p1 = rowptr[d[1]] + r.y;
    int p2 = rowptr[d[2]] + r.z;
    int p3 = rowptr[d[3]] + r.w;
    srcs[p0] = s[0];
    srcs[p1] = s[1];
    srcs[p2] = s[2];
    srcs[p3] = s[3];
}

// ---------- W1 prep: pack into MFMA fragment order, split hi/lo bf16 ----------
__global__ void k_prepw(const float* __restrict__ W, unsigned short* __restrict__ wh,
                        unsigned short* __restrict__ wl) {
    int t = blockIdx.x * 256 + threadIdx.x;
    if (t >= KSTEPS * 4 * 64) return;
    int l = t & 63;
    int f = (t >> 6) & 3;
    int s = t >> 8;
    int n = f * 16 + (l & 15);
    int kbase = s * 32 + 8 * (l >> 4);
    unsigned short* ph = wh + (size_t)t * 8;
    unsigned short* pl = wl + (size_t)t * 8;
    #pragma unroll
    for (int j = 0; j < 8; ++j) {
        int k = kbase + j;
        float v = (k < IND) ? W[(size_t)k * HD + n] : 0.f;
        unsigned u = __float_as_uint(v);
        unsigned short hb = (unsigned short)(u >> 16);              // trunc hi
        float r = v - __uint_as_float(u & 0xffff0000u);
        ph[j] = hb;
        pl[j] = f2bf(r);
    }
}

// ---------- GEMM1 (MFMA): hs[i] = bf16( dinv[i] * (x @ W1)[i] ) ----------
// 16 rows per wave -> 6250 waves (grid-starved fix); batched B loads (8-deep MLP)
struct XF { float4 a, b; };
static __device__ __forceinline__ XF ldx(const float* p) {
    XF r; r.a = *(const float4*)p; r.b = *(const float4*)(p + 4); return r;
}
static __device__ __forceinline__ XF ldx_tail(const float* p, int k0) {
    float t[8];
    #pragma unroll
    for (int j = 0; j < 8; ++j) t[j] = (k0 + j < IND) ? p[j] : 0.f;
    XF r;
    r.a = make_float4(t[0], t[1], t[2], t[3]);
    r.b = make_float4(t[4], t[5], t[6], t[7]);
    return r;
}
static __device__ __forceinline__ void split8(const XF& u, short8v& hi, short8v& lo) {
    float t[8] = {u.a.x, u.a.y, u.a.z, u.a.w, u.b.x, u.b.y, u.b.z, u.b.w};
    #pragma unroll
    for (int j = 0; j < 8; ++j) {
        unsigned q = __float_as_uint(t[j]);
        hi[j] = (short)(q >> 16);
        float r = t[j] - __uint_as_float(q & 0xffff0000u);
        lo[j] = (short)f2bf(r);
    }
}

__global__ __launch_bounds__(256) void k_gemm1m(const float* __restrict__ x,
                                                const short8v* __restrict__ wh,
                                                const short8v* __restrict__ wl,
                                                const float* __restrict__ dinv,
                                                unsigned short* __restrict__ h) {
    const int lane = threadIdx.x & 63;
    const int wave = threadIdx.x >> 6;
    const int row0 = (blockIdx.x * 4 + wave) * 16;
    if (row0 >= NN) return;
    const int rA = lane & 15;
    const int cg = lane >> 4;
    const bool tailw = (row0 == NN - 16);   // wave containing the last row

    float4v acc[4];
    const float4v zero4 = {0.f, 0.f, 0.f, 0.f};
    #pragma unroll
    for (int f = 0; f < 4; ++f) acc[f] = zero4;

    const float* xq = x + (size_t)(row0 + rA) * IND + cg * 8;

    XF cur = ldx(xq);
    #pragma unroll
    for (int s = 0; s < KSTEPS; ++s) {
        XF nxt;
        if (s + 1 < KSTEPS) {
            const float* p = xq + (s + 1) * 32;
            if (s + 1 == KSTEPS - 1 && tailw)
                nxt = ldx_tail(p, (KSTEPS - 1) * 32 + cg * 8);
            else
                nxt = ldx(p);
        }
        // batch all 8 B loads (independent -> 8-deep MLP)
        const short8v* bhp = wh + (size_t)s * 256 + lane;
        const short8v* blp = wl + (size_t)s * 256 + lane;
        short8v vh[4], vl[4];
        #pragma unroll
        for (int f = 0; f < 4; ++f) {
            vh[f] = bhp[(size_t)f * 64];
            vl[f] = blp[(size_t)f * 64];
        }
        short8v ah, al;
        split8(cur, ah, al);
        #pragma unroll
        for (int f = 0; f < 4; ++f) {
            acc[f] = mfma16(al, vh[f], acc[f]);
            acc[f] = mfma16(ah, vl[f], acc[f]);
            acc[f] = mfma16(ah, vh[f], acc[f]);
        }
        cur = nxt;
    }

    // C/D layout (m89-verified): col = lane&15, row = (lane>>4)*4 + reg
    #pragma unroll
    for (int j = 0; j < 4; ++j) {
        int row = row0 + cg * 4 + j;
        float dv = dinv[row];
        #pragma unroll
        for (int f = 0; f < 4; ++f)
            h[(size_t)row * HD + f * 16 + rA] = f2bf(acc[f][j] * dv);
    }
}

// ---------- CSR aggregation: out[d] = dn * sum(hs[s]) ; wave per node, lane = channel ----------
template<bool L1>
__global__ __launch_bounds__(256) void k_agg(const int* __restrict__ rowptr,
                                             const int* __restrict__ srcs,
                                             const float* __restrict__ dinv,
                                             const unsigned short* __restrict__ hb,
                                             const float* __restrict__ bias,
                                             unsigned short* __restrict__ outb,
                                             float* __restrict__ outf) {
    int wid = (blockIdx.x * 256 + threadIdx.x) >> 6;
    int lane = threadIdx.x & 63;
    if (wid >= NN) return;
    float acc = bf2f(hb[(size_t)wid * HD + lane]);   // self loop (hs already dinv-scaled)
    int beg = rowptr[wid];
    int cnt = rowptr[wid + 1] - beg;
    for (int base = 0; base < cnt; base += 64) {
        int m = cnt - base; if (m > 64) m = 64;
        int sj = (lane < m) ? srcs[beg + base + lane] : 0;
        int j = 0;
        for (; j + 8 <= m; j += 8) {
            int s0 = __builtin_amdgcn_readlane(sj, j);
            int s1 = __builtin_amdgcn_readlane(sj, j + 1);
            int s2 = __builtin_amdgcn_readlane(sj, j + 2);
            int s3 = __builtin_amdgcn_readlane(sj, j + 3);
            int s4 = __builtin_amdgcn_readlane(sj, j + 4);
            int s5 = __builtin_amdgcn_readlane(sj, j + 5);
            int s6 = __builtin_amdgcn_readlane(sj, j + 6);
            int s7 = __builtin_amdgcn_readlane(sj, j + 7);
            float v0 = bf2f(hb[(size_t)s0 * HD + lane]);
            float v1 = bf2f(hb[(size_t)s1 * HD + lane]);
            float v2 = bf2f(hb[(size_t)s2 * HD + lane]);
            float v3 = bf2f(hb[(size_t)s3 * HD + lane]);
            float v4 = bf2f(hb[(size_t)s4 * HD + lane]);
            float v5 = bf2f(hb[(size_t)s5 * HD + lane]);
            float v6 = bf2f(hb[(size_t)s6 * HD + lane]);
            float v7 = bf2f(hb[(size_t)s7 * HD + lane]);
            acc += ((v0 + v1) + (v2 + v3)) + ((v4 + v5) + (v6 + v7));
        }
        for (; j < m; ++j) {
            int s = __builtin_amdgcn_readlane(sj, j);
            acc += bf2f(hb[(size_t)s * HD + lane]);
        }
    }
    float dn = dinv[wid];
    acc *= dn;
    if (L1) {
        outb[(size_t)wid * HD + lane] = f2bf(fmaxf(acc + bias[lane], 0.f) * dn);
    } else {
        outf[(size_t)wid * HD + lane] = acc;
    }
}

// ---------- GEMM2 + bias: out = agg2 @ W2 + b2 ----------
__global__ __launch_bounds__(256) void k_gemm2(const float* __restrict__ h,
                                               const float* __restrict__ W2,
                                               const float* __restrict__ b2,
                                               float* __restrict__ out) {
    __shared__ float hs[32][65];
    __shared__ float ws2[64][40];
    const int t = threadIdx.x;
    const int r0 = blockIdx.x * 32;
    for (int i = t; i < 64 * OD; i += 256)
        ws2[i / OD][i % OD] = W2[i];
    for (int i = t; i < 32 * 64; i += 256) {
        int r = i >> 6, k = i & 63;
        hs[r][k] = h[(size_t)(r0 + r) * HD + k];
    }
    __syncthreads();
    for (int o = t; o < 32 * OD; o += 256) {
        int r = o / OD, c = o - r * OD;
        float s = 0.f;
        #pragma unroll
        for (int k = 0; k < HD; ++k)
            s = fmaf(hs[r][k], ws2[k][c], s);
        out[(size_t)(r0 + r) * OD + c] = s + b2[c];
    }
}

extern "C" void kernel_launch(void* const* d_in, const int* in_sizes, int n_in,
                              void* d_out, int out_size, void* d_ws, size_t ws_size,
                              hipStream_t stream) {
    const float* x  = (const float*)d_in[0];
    const float* W1 = (const float*)d_in[1];
    const float* b1 = (const float*)d_in[2];
    const float* W2 = (const float*)d_in[3];
    const float* b2 = (const float*)d_in[4];
    const void*  ei = d_in[5];
    float* out = (float*)d_out;

    // --- scratch carved out of d_out (16 MB); all dead before k_gemm2 writes out ---
    char* ob = (char*)d_out;
    int*   rowptr = (int*)ob;                              // 400,004 B
    int*   cnt    = (int*)(ob + 400896);                   // 400,000 B
    int*   bsum   = (int*)(ob + 801280);                   // 1,564 B
    int*   srcs   = (int*)(ob + 803328);                   // 6,400,000 B (end 7,203,328)
    float* dinv   = (float*)(ob + 7203840);                // 400,000 B (end 7,603,840)
    int*   rank   = (int*)(ob + 7604224);                  // 6,400,000 B (end 14,004,224)
    unsigned short* wh = (unsigned short*)(ob + 14004736); // 65,536 B
    unsigned short* wl = (unsigned short*)(ob + 14070272); // 65,536 B (end 14,135,808 < 16 MB)

    // --- ws: feature matrices (bf16 h, fp32 agg2) ---
    char* ws = (char*)d_ws;
    int*            flags  = (int*)ws;                         // 1 KB
    unsigned short* h1b    = (unsigned short*)(ws + 1024);     // 12.8 MB
    unsigned short* hrelub = (unsigned short*)(ws + 1024 + 12800000); // 12.8 MB
    float*          agg2   = (float*)(ws + 1024 + 25600000);   // 25.6 MB (end 51.2 MB)

    k_detect<<<1, 64, 0, stream>>>((const unsigned*)ei, flags);
    k_prepw<<<(KSTEPS * 4 * 64 + 255) / 256, 256, 0, stream>>>(W1, wh, wl);

    // CSR build: count(+rank) -> scan(+dinv) -> scatter (atomic-free)
    hipMemsetAsync(cnt, 0, (size_t)NN * 4, stream);
    k_count<<<(NE / 4 + 255) / 256, 256, 0, stream>>>(ei, flags, cnt, rank);
    k_scan_block<<<NBLK, 256, 0, stream>>>(cnt, rowptr, bsum, dinv);
    k_scan_bsum<<<1, 512, 0, stream>>>(bsum);
    k_scan_add<<<NBLK, 256, 0, stream>>>(rowptr, bsum);
    k_scatter<<<(NE / 4 + 255) / 256, 256, 0, stream>>>(ei, flags, rowptr, rank, srcs);

    // layer 1: MFMA GEMM (split-bf16, dinv-scaled bf16 output), then CSR aggregation
    k_gemm1m<<<(NN / 16 + 3) / 4, 256, 0, stream>>>(x, (const short8v*)wh, (const short8v*)wl, dinv, h1b);
    k_agg<true><<<(NN * 64) / 256, 256, 0, stream>>>(rowptr, srcs, dinv, h1b, b1, hrelub, (float*)nullptr);

    // layer 2: aggregate first (commutes with linear map), then GEMM+bias
    k_agg<false><<<(NN * 64) / 256, 256, 0, stream>>>(rowptr, srcs, dinv, hrelub, (const float*)nullptr, (unsigned short*)nullptr, agg2);
    k_gemm2<<<NN / 32, 256, 0, stream>>>(agg2, W2, b2, out);
}

// Round 6
// 349.829 us; speedup vs baseline: 1.0025x; 1.0025x over previous
//
#include <hip/hip_runtime.h>
#include <cstdint>
#include <cstddef>

#define NN 100000
#define NE 1600000
#define IND 500
#define HD 64
#define OD 40
#define NBLK ((NN + 255) / 256)   // 391 scan blocks
#define KSTEPS 16                 // ceil(500/32)

typedef __attribute__((ext_vector_type(8))) short short8v;
typedef __attribute__((ext_vector_type(8))) __bf16 bf16x8;
typedef __attribute__((ext_vector_type(4))) float float4v;

// MFMA builtin signature differs across toolchains (short8 vs bf16x8).
template <class V>
static __device__ __forceinline__ auto mfma_bf16_(V a, V b, float4v c, int)
    -> decltype(__builtin_amdgcn_mfma_f32_16x16x32_bf16(a, b, c, 0, 0, 0)) {
    return __builtin_amdgcn_mfma_f32_16x16x32_bf16(a, b, c, 0, 0, 0);
}
template <class V>
static __device__ __forceinline__ float4v mfma_bf16_(V a, V b, float4v c, long) {
    return __builtin_amdgcn_mfma_f32_16x16x32_bf16((bf16x8)a, (bf16x8)b, c, 0, 0, 0);
}
static __device__ __forceinline__ float4v mfma16(short8v a, short8v b, float4v c) {
    return mfma_bf16_(a, b, c, 0);
}

static __device__ __forceinline__ float bf2f(unsigned short v) {
    return __uint_as_float((unsigned)v << 16);
}
static __device__ __forceinline__ unsigned short f2bf(float v) {
    unsigned u = __float_as_uint(v);
    return (unsigned short)((u + 0x7fffu + ((u >> 16) & 1u)) >> 16);
}

// ---------- edge loading (int32 vs int64 auto-detect) ----------
__global__ void k_detect(const unsigned* ei32, int* flags) {
    if (threadIdx.x == 0 && blockIdx.x == 0) {
        int is64 = 1;
        #pragma unroll
        for (int i = 1; i < 16; i += 2)
            if (ei32[i] != 0u) is64 = 0;
        flags[0] = is64;
    }
}

// load 4 consecutive edge entries starting at element index base (base % 4 == 0)
static __device__ __forceinline__ void load4e(const void* ei, int is64, size_t base, int v[4]) {
    if (is64) {
        int4 a = ((const int4*)ei)[base >> 1];
        int4 b = ((const int4*)ei)[(base >> 1) + 1];
        v[0] = a.x; v[1] = a.z; v[2] = b.x; v[3] = b.z;
    } else {
        int4 a = *(const int4*)((const int*)ei + base);
        v[0] = a.x; v[1] = a.y; v[2] = a.z; v[3] = a.w;
    }
}

// ---------- degree histogram + per-edge rank (atomic return value) ----------
__global__ void k_count(const void* ei, const int* __restrict__ flags, int* cnt,
                        int* __restrict__ rank) {
    int e0 = (blockIdx.x * 256 + threadIdx.x) * 4;
    if (e0 >= NE) return;
    int d[4];
    load4e(ei, flags[0], (size_t)NE + e0, d);
    int4 r;
    r.x = atomicAdd(&cnt[d[0]], 1);
    r.y = atomicAdd(&cnt[d[1]], 1);
    r.z = atomicAdd(&cnt[d[2]], 1);
    r.w = atomicAdd(&cnt[d[3]], 1);
    *(int4*)(rank + e0) = r;
}

// ---------- exclusive scan (3 kernels); dinv fused into pass 1 ----------
__global__ __launch_bounds__(256) void k_scan_block(const int* __restrict__ cnt,
                                                    int* __restrict__ rowptr,
                                                    int* __restrict__ bsum,
                                                    float* __restrict__ dinv) {
    int t = threadIdx.x;
    int i = blockIdx.x * 256 + t;
    int v = (i < NN) ? cnt[i] : 0;
    if (i < NN) dinv[i] = rsqrtf((float)v + 1.0f);   // +1 = self loop
    int inc = v;
    #pragma unroll
    for (int off = 1; off < 64; off <<= 1) {
        int u = __shfl_up(inc, off);
        if ((t & 63) >= off) inc += u;
    }
    __shared__ int wsum[4];
    if ((t & 63) == 63) wsum[t >> 6] = inc;
    __syncthreads();
    if (t == 0) {
        int a = 0;
        #pragma unroll
        for (int w = 0; w < 4; ++w) { int b = wsum[w]; wsum[w] = a; a += b; }
        bsum[blockIdx.x] = a;
    }
    __syncthreads();
    if (i < NN) rowptr[i] = inc - v + wsum[t >> 6];
}

__global__ __launch_bounds__(512) void k_scan_bsum(int* bsum) {
    int t = threadIdx.x;
    int v = (t < NBLK) ? bsum[t] : 0;
    int inc = v;
    #pragma unroll
    for (int off = 1; off < 64; off <<= 1) {
        int u = __shfl_up(inc, off);
        if ((t & 63) >= off) inc += u;
    }
    __shared__ int wsum[8];
    if ((t & 63) == 63) wsum[t >> 6] = inc;
    __syncthreads();
    if (t == 0) {
        int a = 0;
        #pragma unroll
        for (int w = 0; w < 8; ++w) { int b = wsum[w]; wsum[w] = a; a += b; }
    }
    __syncthreads();
    if (t < NBLK) bsum[t] = inc - v + wsum[t >> 6];
}

__global__ void k_scan_add(int* rowptr, const int* __restrict__ bsum) {
    int i = blockIdx.x * 256 + threadIdx.x;
    if (i < NN) rowptr[i] += bsum[i >> 8];
    if (i == 0) rowptr[NN] = NE;
}

// ---------- counting-sort scatter (no atomics: pos = rowptr[d] + rank[e]) ----------
__global__ void k_scatter(const void* ei, const int* __restrict__ flags,
                          const int* __restrict__ rowptr, const int* __restrict__ rank,
                          int* __restrict__ srcs) {
    int e0 = (blockIdx.x * 256 + threadIdx.x) * 4;
    if (e0 >= NE) return;
    int is64 = flags[0];
    int s[4], d[4];
    load4e(ei, is64, (size_t)e0, s);
    load4e(ei, is64, (size_t)NE + e0, d);
    int4 r = *(const int4*)(rank + e0);
    int p0 = rowptr[d[0]] + r.x;
    int p1 = rowptr[d[1]] + r.y;
    int p2 = rowptr[d[2]] + r.z;
    int p3 = rowptr[d[3]] + r.w;
    srcs[p0] = s[0];
    srcs[p1] = s[1];
    srcs[p2] = s[2];
    srcs[p3] = s[3];
}

// ---------- W1 prep: pack into MFMA fragment order, split hi/lo bf16 ----------
__global__ void k_prepw(const float* __restrict__ W, unsigned short* __restrict__ wh,
                        unsigned short* __restrict__ wl) {
    int t = blockIdx.x * 256 + threadIdx.x;
    if (t >= KSTEPS * 4 * 64) return;
    int l = t & 63;
    int f = (t >> 6) & 3;
    int s = t >> 8;
    int n = f * 16 + (l & 15);
    int kbase = s * 32 + 8 * (l >> 4);
    unsigned short* ph = wh + (size_t)t * 8;
    unsigned short* pl = wl + (size_t)t * 8;
    #pragma unroll
    for (int j = 0; j < 8; ++j) {
        int k = kbase + j;
        float v = (k < IND) ? W[(size_t)k * HD + n] : 0.f;
        unsigned u = __float_as_uint(v);
        unsigned short hb = (unsigned short)(u >> 16);              // trunc hi
        float r = v - __uint_as_float(u & 0xffff0000u);
        ph[j] = hb;
        pl[j] = f2bf(r);
    }
}

// ---------- GEMM1 (MFMA): hs[i] = bf16( dinv[i] * (x @ W1)[i] ) ----------
struct XF { float4 a, b; };
static __device__ __forceinline__ XF ldx(const float* p) {
    XF r; r.a = *(const float4*)p; r.b = *(const float4*)(p + 4); return r;
}
static __device__ __forceinline__ XF ldx_tail(const float* p, int k0) {
    float t[8];
    #pragma unroll
    for (int j = 0; j < 8; ++j) t[j] = (k0 + j < IND) ? p[j] : 0.f;
    XF r;
    r.a = make_float4(t[0], t[1], t[2], t[3]);
    r.b = make_float4(t[4], t[5], t[6], t[7]);
    return r;
}
static __device__ __forceinline__ void split8(const XF& u, short8v& hi, short8v& lo) {
    float t[8] = {u.a.x, u.a.y, u.a.z, u.a.w, u.b.x, u.b.y, u.b.z, u.b.w};
    #pragma unroll
    for (int j = 0; j < 8; ++j) {
        unsigned q = __float_as_uint(t[j]);
        hi[j] = (short)(q >> 16);
        float r = t[j] - __uint_as_float(q & 0xffff0000u);
        lo[j] = (short)f2bf(r);
    }
}

// __launch_bounds__(256, 4): VGPR budget 128 (4 waves/SIMD guaranteed).
// Without this the compiler capped VGPRs at 48-64 and SPILLED the batched
// B-fragments + prefetch regs to scratch inside the K-loop (rounds 3-5 all
// stuck at ~120us with all pipes idle).
__global__ __launch_bounds__(256, 4) void k_gemm1m(const float* __restrict__ x,
                                                   const short8v* __restrict__ wh,
                                                   const short8v* __restrict__ wl,
                                                   const float* __restrict__ dinv,
                                                   unsigned short* __restrict__ h) {
    const int lane = threadIdx.x & 63;
    const int wave = threadIdx.x >> 6;
    const int row0 = (blockIdx.x * 4 + wave) * 16;
    if (row0 >= NN) return;
    const int rA = lane & 15;
    const int cg = lane >> 4;
    const bool tailw = (row0 == NN - 16);   // wave containing the last row

    float4v acc[4];
    const float4v zero4 = {0.f, 0.f, 0.f, 0.f};
    #pragma unroll
    for (int f = 0; f < 4; ++f) acc[f] = zero4;

    const float* xq = x + (size_t)(row0 + rA) * IND + cg * 8;

    XF cur = ldx(xq);
    #pragma unroll 4
    for (int s = 0; s < KSTEPS; ++s) {
        XF nxt;
        if (s + 1 < KSTEPS) {
            const float* p = xq + (s + 1) * 32;
            if (s + 1 == KSTEPS - 1 && tailw)
                nxt = ldx_tail(p, (KSTEPS - 1) * 32 + cg * 8);
            else
                nxt = ldx(p);
        }
        // batch all 8 B loads (independent -> 8-deep MLP)
        const short8v* bhp = wh + (size_t)s * 256 + lane;
        const short8v* blp = wl + (size_t)s * 256 + lane;
        short8v vh[4], vl[4];
        #pragma unroll
        for (int f = 0; f < 4; ++f) {
            vh[f] = bhp[(size_t)f * 64];
            vl[f] = blp[(size_t)f * 64];
        }
        short8v ah, al;
        split8(cur, ah, al);
        #pragma unroll
        for (int f = 0; f < 4; ++f) {
            acc[f] = mfma16(al, vh[f], acc[f]);
            acc[f] = mfma16(ah, vl[f], acc[f]);
            acc[f] = mfma16(ah, vh[f], acc[f]);
        }
        cur = nxt;
    }

    // C/D layout (m89-verified): col = lane&15, row = (lane>>4)*4 + reg
    #pragma unroll
    for (int j = 0; j < 4; ++j) {
        int row = row0 + cg * 4 + j;
        float dv = dinv[row];
        #pragma unroll
        for (int f = 0; f < 4; ++f)
            h[(size_t)row * HD + f * 16 + rA] = f2bf(acc[f][j] * dv);
    }
}

// ---------- CSR aggregation: out[d] = dn * sum(hs[s]) ; wave per node, lane = channel ----------
template<bool L1>
__global__ __launch_bounds__(256) void k_agg(const int* __restrict__ rowptr,
                                             const int* __restrict__ srcs,
                                             const float* __restrict__ dinv,
                                             const unsigned short* __restrict__ hb,
                                             const float* __restrict__ bias,
                                             unsigned short* __restrict__ outb,
                                             float* __restrict__ outf) {
    int wid = (blockIdx.x * 256 + threadIdx.x) >> 6;
    int lane = threadIdx.x & 63;
    if (wid >= NN) return;
    float acc = bf2f(hb[(size_t)wid * HD + lane]);   // self loop (hs already dinv-scaled)
    int beg = rowptr[wid];
    int cnt = rowptr[wid + 1] - beg;
    for (int base = 0; base < cnt; base += 64) {
        int m = cnt - base; if (m > 64) m = 64;
        int sj = (lane < m) ? srcs[beg + base + lane] : 0;
        int j = 0;
        for (; j + 8 <= m; j += 8) {
            int s0 = __builtin_amdgcn_readlane(sj, j);
            int s1 = __builtin_amdgcn_readlane(sj, j + 1);
            int s2 = __builtin_amdgcn_readlane(sj, j + 2);
            int s3 = __builtin_amdgcn_readlane(sj, j + 3);
            int s4 = __builtin_amdgcn_readlane(sj, j + 4);
            int s5 = __builtin_amdgcn_readlane(sj, j + 5);
            int s6 = __builtin_amdgcn_readlane(sj, j + 6);
            int s7 = __builtin_amdgcn_readlane(sj, j + 7);
            float v0 = bf2f(hb[(size_t)s0 * HD + lane]);
            float v1 = bf2f(hb[(size_t)s1 * HD + lane]);
            float v2 = bf2f(hb[(size_t)s2 * HD + lane]);
            float v3 = bf2f(hb[(size_t)s3 * HD + lane]);
            float v4 = bf2f(hb[(size_t)s4 * HD + lane]);
            float v5 = bf2f(hb[(size_t)s5 * HD + lane]);
            float v6 = bf2f(hb[(size_t)s6 * HD + lane]);
            float v7 = bf2f(hb[(size_t)s7 * HD + lane]);
            acc += ((v0 + v1) + (v2 + v3)) + ((v4 + v5) + (v6 + v7));
        }
        for (; j < m; ++j) {
            int s = __builtin_amdgcn_readlane(sj, j);
            acc += bf2f(hb[(size_t)s * HD + lane]);
        }
    }
    float dn = dinv[wid];
    acc *= dn;
    if (L1) {
        outb[(size_t)wid * HD + lane] = f2bf(fmaxf(acc + bias[lane], 0.f) * dn);
    } else {
        outf[(size_t)wid * HD + lane] = acc;
    }
}

// ---------- GEMM2 + bias: out = agg2 @ W2 + b2 ----------
__global__ __launch_bounds__(256) void k_gemm2(const float* __restrict__ h,
                                               const float* __restrict__ W2,
                                               const float* __restrict__ b2,
                                               float* __restrict__ out) {
    __shared__ float hs[32][65];
    __shared__ float ws2[64][40];
    const int t = threadIdx.x;
    const int r0 = blockIdx.x * 32;
    for (int i = t; i < 64 * OD; i += 256)
        ws2[i / OD][i % OD] = W2[i];
    for (int i = t; i < 32 * 64; i += 256) {
        int r = i >> 6, k = i & 63;
        hs[r][k] = h[(size_t)(r0 + r) * HD + k];
    }
    __syncthreads();
    for (int o = t; o < 32 * OD; o += 256) {
        int r = o / OD, c = o - r * OD;
        float s = 0.f;
        #pragma unroll
        for (int k = 0; k < HD; ++k)
            s = fmaf(hs[r][k], ws2[k][c], s);
        out[(size_t)(r0 + r) * OD + c] = s + b2[c];
    }
}

extern "C" void kernel_launch(void* const* d_in, const int* in_sizes, int n_in,
                              void* d_out, int out_size, void* d_ws, size_t ws_size,
                              hipStream_t stream) {
    const float* x  = (const float*)d_in[0];
    const float* W1 = (const float*)d_in[1];
    const float* b1 = (const float*)d_in[2];
    const float* W2 = (const float*)d_in[3];
    const float* b2 = (const float*)d_in[4];
    const void*  ei = d_in[5];
    float* out = (float*)d_out;

    // --- scratch carved out of d_out (16 MB); all dead before k_gemm2 writes out ---
    char* ob = (char*)d_out;
    int*   rowptr = (int*)ob;                              // 400,004 B
    int*   cnt    = (int*)(ob + 400896);                   // 400,000 B
    int*   bsum   = (int*)(ob + 801280);                   // 1,564 B
    int*   srcs   = (int*)(ob + 803328);                   // 6,400,000 B (end 7,203,328)
    float* dinv   = (float*)(ob + 7203840);                // 400,000 B (end 7,603,840)
    int*   rank   = (int*)(ob + 7604224);                  // 6,400,000 B (end 14,004,224)
    unsigned short* wh = (unsigned short*)(ob + 14004736); // 65,536 B
    unsigned short* wl = (unsigned short*)(ob + 14070272); // 65,536 B (end 14,135,808 < 16 MB)

    // --- ws: feature matrices (bf16 h, fp32 agg2) ---
    char* ws = (char*)d_ws;
    int*            flags  = (int*)ws;                         // 1 KB
    unsigned short* h1b    = (unsigned short*)(ws + 1024);     // 12.8 MB
    unsigned short* hrelub = (unsigned short*)(ws + 1024 + 12800000); // 12.8 MB
    float*          agg2   = (float*)(ws + 1024 + 25600000);   // 25.6 MB (end 51.2 MB)

    k_detect<<<1, 64, 0, stream>>>((const unsigned*)ei, flags);
    k_prepw<<<(KSTEPS * 4 * 64 + 255) / 256, 256, 0, stream>>>(W1, wh, wl);

    // CSR build: count(+rank) -> scan(+dinv) -> scatter (atomic-free)
    hipMemsetAsync(cnt, 0, (size_t)NN * 4, stream);
    k_count<<<(NE / 4 + 255) / 256, 256, 0, stream>>>(ei, flags, cnt, rank);
    k_scan_block<<<NBLK, 256, 0, stream>>>(cnt, rowptr, bsum, dinv);
    k_scan_bsum<<<1, 512, 0, stream>>>(bsum);
    k_scan_add<<<NBLK, 256, 0, stream>>>(rowptr, bsum);
    k_scatter<<<(NE / 4 + 255) / 256, 256, 0, stream>>>(ei, flags, rowptr, rank, srcs);

    // layer 1: MFMA GEMM (split-bf16, dinv-scaled bf16 output), then CSR aggregation
    k_gemm1m<<<(NN / 16 + 3) / 4, 256, 0, stream>>>(x, (const short8v*)wh, (const short8v*)wl, dinv, h1b);
    k_agg<true><<<(NN * 64) / 256, 256, 0, stream>>>(rowptr, srcs, dinv, h1b, b1, hrelub, (float*)nullptr);

    // layer 2: aggregate first (commutes with linear map), then GEMM+bias
    k_agg<false><<<(NN * 64) / 256, 256, 0, stream>>>(rowptr, srcs, dinv, hrelub, (const float*)nullptr, (unsigned short*)nullptr, agg2);
    k_gemm2<<<NN / 32, 256, 0, stream>>>(agg2, W2, b2, out);
}

// Round 7
// 324.776 us; speedup vs baseline: 1.0798x; 1.0771x over previous
//
#include <hip/hip_runtime.h>
#include <cstdint>
#include <cstddef>

#define NN 100000
#define NE 1600000
#define IND 500
#define HD 64
#define OD 40
#define NBLK ((NN + 255) / 256)   // 391 scan blocks
#define KSTEPS 16                 // ceil(500/32)
#define BK 64                     // k-tile (2 MFMA k-steps)
#define NT 8                      // ceil(500/64)

typedef __attribute__((ext_vector_type(8))) short short8v;
typedef __attribute__((ext_vector_type(8))) __bf16 bf16x8;
typedef __attribute__((ext_vector_type(4))) float float4v;

// MFMA builtin signature differs across toolchains (short8 vs bf16x8).
template <class V>
static __device__ __forceinline__ auto mfma_bf16_(V a, V b, float4v c, int)
    -> decltype(__builtin_amdgcn_mfma_f32_16x16x32_bf16(a, b, c, 0, 0, 0)) {
    return __builtin_amdgcn_mfma_f32_16x16x32_bf16(a, b, c, 0, 0, 0);
}
template <class V>
static __device__ __forceinline__ float4v mfma_bf16_(V a, V b, float4v c, long) {
    return __builtin_amdgcn_mfma_f32_16x16x32_bf16((bf16x8)a, (bf16x8)b, c, 0, 0, 0);
}
static __device__ __forceinline__ float4v mfma16(short8v a, short8v b, float4v c) {
    return mfma_bf16_(a, b, c, 0);
}

static __device__ __forceinline__ float bf2f(unsigned short v) {
    return __uint_as_float((unsigned)v << 16);
}
static __device__ __forceinline__ unsigned short f2bf(float v) {
    unsigned u = __float_as_uint(v);
    return (unsigned short)((u + 0x7fffu + ((u >> 16) & 1u)) >> 16);
}

// global -> LDS DMA, 16B per lane; dest = wave-uniform base + lane*16
typedef __attribute__((address_space(3))) char lds_char;
typedef const __attribute__((address_space(1))) char g_char;
static __device__ __forceinline__ void gl16(const char* g, char* l) {
    __builtin_amdgcn_global_load_lds((g_char*)g, (lds_char*)l, 16, 0, 0);
}

// ---------- edge loading (int32 vs int64 auto-detect) ----------
__global__ void k_detect(const unsigned* ei32, int* flags) {
    if (threadIdx.x == 0 && blockIdx.x == 0) {
        int is64 = 1;
        #pragma unroll
        for (int i = 1; i < 16; i += 2)
            if (ei32[i] != 0u) is64 = 0;
        flags[0] = is64;
    }
}

// load 4 consecutive edge entries starting at element index base (base % 4 == 0)
static __device__ __forceinline__ void load4e(const void* ei, int is64, size_t base, int v[4]) {
    if (is64) {
        int4 a = ((const int4*)ei)[base >> 1];
        int4 b = ((const int4*)ei)[(base >> 1) + 1];
        v[0] = a.x; v[1] = a.z; v[2] = b.x; v[3] = b.z;
    } else {
        int4 a = *(const int4*)((const int*)ei + base);
        v[0] = a.x; v[1] = a.y; v[2] = a.z; v[3] = a.w;
    }
}

// ---------- degree histogram + per-edge rank (atomic return value) ----------
__global__ void k_count(const void* ei, const int* __restrict__ flags, int* cnt,
                        int* __restrict__ rank) {
    int e0 = (blockIdx.x * 256 + threadIdx.x) * 4;
    if (e0 >= NE) return;
    int d[4];
    load4e(ei, flags[0], (size_t)NE + e0, d);
    int4 r;
    r.x = atomicAdd(&cnt[d[0]], 1);
    r.y = atomicAdd(&cnt[d[1]], 1);
    r.z = atomicAdd(&cnt[d[2]], 1);
    r.w = atomicAdd(&cnt[d[3]], 1);
    *(int4*)(rank + e0) = r;
}

// ---------- exclusive scan (3 kernels); dinv fused into pass 1 ----------
__global__ __launch_bounds__(256) void k_scan_block(const int* __restrict__ cnt,
                                                    int* __restrict__ rowptr,
                                                    int* __restrict__ bsum,
                                                    float* __restrict__ dinv) {
    int t = threadIdx.x;
    int i = blockIdx.x * 256 + t;
    int v = (i < NN) ? cnt[i] : 0;
    if (i < NN) dinv[i] = rsqrtf((float)v + 1.0f);   // +1 = self loop
    int inc = v;
    #pragma unroll
    for (int off = 1; off < 64; off <<= 1) {
        int u = __shfl_up(inc, off);
        if ((t & 63) >= off) inc += u;
    }
    __shared__ int wsum[4];
    if ((t & 63) == 63) wsum[t >> 6] = inc;
    __syncthreads();
    if (t == 0) {
        int a = 0;
        #pragma unroll
        for (int w = 0; w < 4; ++w) { int b = wsum[w]; wsum[w] = a; a += b; }
        bsum[blockIdx.x] = a;
    }
    __syncthreads();
    if (i < NN) rowptr[i] = inc - v + wsum[t >> 6];
}

__global__ __launch_bounds__(512) void k_scan_bsum(int* bsum) {
    int t = threadIdx.x;
    int v = (t < NBLK) ? bsum[t] : 0;
    int inc = v;
    #pragma unroll
    for (int off = 1; off < 64; off <<= 1) {
        int u = __shfl_up(inc, off);
        if ((t & 63) >= off) inc += u;
    }
    __shared__ int wsum[8];
    if ((t & 63) == 63) wsum[t >> 6] = inc;
    __syncthreads();
    if (t == 0) {
        int a = 0;
        #pragma unroll
        for (int w = 0; w < 8; ++w) { int b = wsum[w]; wsum[w] = a; a += b; }
    }
    __syncthreads();
    if (t < NBLK) bsum[t] = inc - v + wsum[t >> 6];
}

__global__ void k_scan_add(int* rowptr, const int* __restrict__ bsum) {
    int i = blockIdx.x * 256 + threadIdx.x;
    if (i < NN) rowptr[i] += bsum[i >> 8];
    if (i == 0) rowptr[NN] = NE;
}

// ---------- counting-sort scatter (no atomics: pos = rowptr[d] + rank[e]) ----------
__global__ void k_scatter(const void* ei, const int* __restrict__ flags,
                          const int* __restrict__ rowptr, const int* __restrict__ rank,
                          int* __restrict__ srcs) {
    int e0 = (blockIdx.x * 256 + threadIdx.x) * 4;
    if (e0 >= NE) return;
    int is64 = flags[0];
    int s[4], d[4];
    load4e(ei, is64, (size_t)e0, s);
    load4e(ei, is64, (size_t)NE + e0, d);
    int4 r = *(const int4*)(rank + e0);
    int p0 = rowptr[d[0]] + r.x;
    int p1 = rowptr[d[1]] + r.y;
    int p2 = rowptr[d[2]] + r.z;
    int p3 = rowptr[d[3]] + r.w;
    srcs[p0] = s[0];
    srcs[p1] = s[1];
    srcs[p2] = s[2];
    srcs[p3] = s[3];
}

// ---------- W1 prep: pack into MFMA fragment order, split hi/lo bf16 ----------
// frag index t = (s*4 + f)*64 + lane; lane holds n = f*16+(lane&15), k = s*32+8*(lane>>4)+j
__global__ void k_prepw(const float* __restrict__ W, unsigned short* __restrict__ wh,
                        unsigned short* __restrict__ wl) {
    int t = blockIdx.x * 256 + threadIdx.x;
    if (t >= KSTEPS * 4 * 64) return;
    int l = t & 63;
    int f = (t >> 6) & 3;
    int s = t >> 8;
    int n = f * 16 + (l & 15);
    int kbase = s * 32 + 8 * (l >> 4);
    unsigned short* ph = wh + (size_t)t * 8;
    unsigned short* pl = wl + (size_t)t * 8;
    #pragma unroll
    for (int j = 0; j < 8; ++j) {
        int k = kbase + j;
        float v = (k < IND) ? W[(size_t)k * HD + n] : 0.f;
        unsigned u = __float_as_uint(v);
        unsigned short hb = (unsigned short)(u >> 16);              // trunc hi
        float r = v - __uint_as_float(u & 0xffff0000u);
        ph[j] = hb;
        pl[j] = f2bf(r);
    }
}

// ---------- GEMM1 (MFMA + global_load_lds staging) ----------
// hs[i] = bf16( dinv[i] * (x @ W1)[i] )
// block = 4 waves = 64 rows; k-tile BK=64 double-buffered in LDS.
// A tile [64 rows][16 chunks of 16B], chunk XOR-swizzled by (row&7) at the
// SOURCE address (global_load_lds writes linearly; m173 pattern) so the
// per-row ds_reads spread across banks.
static __device__ __forceinline__ void split8f(float4 u0, float4 u1,
                                               short8v& hi, short8v& lo) {
    float t[8] = {u0.x, u0.y, u0.z, u0.w, u1.x, u1.y, u1.z, u1.w};
    #pragma unroll
    for (int j = 0; j < 8; ++j) {
        unsigned q = __float_as_uint(t[j]);
        hi[j] = (short)(q >> 16);
        float r = t[j] - __uint_as_float(q & 0xffff0000u);
        lo[j] = (short)f2bf(r);
    }
}

__global__ __launch_bounds__(256, 2) void k_gemm1m(const float* __restrict__ x,
                                                   const char* __restrict__ whb,
                                                   const char* __restrict__ wlb,
                                                   const float* __restrict__ dinv,
                                                   unsigned short* __restrict__ h) {
    __shared__ char smem[65536];   // A: [0,32K) two 16K bufs; B: [32K,64K) two 16K bufs
    const int tid  = threadIdx.x;
    const int lane = tid & 63;
    const int wave = tid >> 6;
    const int row0 = blockIdx.x * 64;
    const int rA = lane & 15;
    const int cg = lane >> 4;

    // ---- staging: 8x global_load_lds(16B) per thread per k-tile ----
    auto stage = [&](int kt, int buf, bool tail) {
        #pragma unroll
        for (int i = 0; i < 4; ++i) {           // A: 1024 slots of 16B
            int slot = i * 256 + tid;
            int r = slot >> 4, c = slot & 15;
            int cs = c ^ (r & 7);               // pre-swizzled source chunk
            if (tail && cs > 12) cs = 12;       // clamp: finite dup data * W-pad(0) = 0
            int rsrc = row0 + r; if (rsrc >= NN) rsrc = NN - 1;
            const char* g = (const char*)x + (size_t)rsrc * (IND * 4) + kt * 256 + cs * 16;
            char* l = smem + buf * 16384 + (i * 256 + wave * 64) * 16;
            gl16(g, l);
        }
        #pragma unroll
        for (int i = 0; i < 4; ++i) {           // B: wh 512 slots + wl 512 slots, linear
            int j = i * 256 + tid;
            const char* src = (j < 512 ? whb : wlb) + kt * 8192 + (size_t)(j & 511) * 16;
            char* l = smem + 32768 + buf * 16384 + (i * 256 + wave * 64) * 16;
            gl16(src, l);
        }
    };

    float4v acc[4];
    const float4v zero4 = {0.f, 0.f, 0.f, 0.f};
    #pragma unroll
    for (int f = 0; f < 4; ++f) acc[f] = zero4;

    stage(0, 0, false);
    __syncthreads();                            // vmcnt(0) drain + barrier

    int cur = 0;
    const int rb16 = (wave * 16 + rA) * 16;     // A row base, in float4 units
    const int sw = rA & 7;

    for (int kt = 0; kt < NT; ++kt) {
        if (kt + 1 < NT) stage(kt + 1, cur ^ 1, kt + 1 == NT - 1);
        const float4*  pa = (const float4*)(smem + cur * 16384);
        const short8v* pb = (const short8v*)(smem + 32768 + cur * 16384);
        #pragma unroll
        for (int kk = 0; kk < 2; ++kk) {
            int ch = kk * 8 + cg * 2;
            float4 u0 = pa[rb16 + (ch ^ sw)];
            float4 u1 = pa[rb16 + ((ch + 1) ^ sw)];
            short8v ah, al;
            split8f(u0, u1, ah, al);
            #pragma unroll
            for (int f = 0; f < 4; ++f) {
                short8v vh = pb[kk * 256 + f * 64 + lane];
                short8v vl = pb[512 + kk * 256 + f * 64 + lane];
                acc[f] = mfma16(al, vh, acc[f]);
                acc[f] = mfma16(ah, vl, acc[f]);
                acc[f] = mfma16(ah, vh, acc[f]);
            }
        }
        __syncthreads();                        // drain stage(kt+1) + barrier
        cur ^= 1;
    }

    // C/D layout (m89-verified): col = lane&15, row = (lane>>4)*4 + reg
    #pragma unroll
    for (int j = 0; j < 4; ++j) {
        int row = row0 + wave * 16 + cg * 4 + j;
        if (row < NN) {
            float dv = dinv[row];
            #pragma unroll
            for (int f = 0; f < 4; ++f)
                h[(size_t)row * HD + f * 16 + rA] = f2bf(acc[f][j] * dv);
        }
    }
}

// ---------- CSR aggregation: out[d] = dn * sum(hs[s]) ; wave per node, lane = channel ----------
template<bool L1>
__global__ __launch_bounds__(256) void k_agg(const int* __restrict__ rowptr,
                                             const int* __restrict__ srcs,
                                             const float* __restrict__ dinv,
                                             const unsigned short* __restrict__ hb,
                                             const float* __restrict__ bias,
                                             unsigned short* __restrict__ outb,
                                             float* __restrict__ outf) {
    int wid = (blockIdx.x * 256 + threadIdx.x) >> 6;
    int lane = threadIdx.x & 63;
    if (wid >= NN) return;
    float acc = bf2f(hb[(size_t)wid * HD + lane]);   // self loop (hs already dinv-scaled)
    int beg = rowptr[wid];
    int cnt = rowptr[wid + 1] - beg;
    for (int base = 0; base < cnt; base += 64) {
        int m = cnt - base; if (m > 64) m = 64;
        int sj = (lane < m) ? srcs[beg + base + lane] : 0;
        int j = 0;
        for (; j + 8 <= m; j += 8) {
            int s0 = __builtin_amdgcn_readlane(sj, j);
            int s1 = __builtin_amdgcn_readlane(sj, j + 1);
            int s2 = __builtin_amdgcn_readlane(sj, j + 2);
            int s3 = __builtin_amdgcn_readlane(sj, j + 3);
            int s4 = __builtin_amdgcn_readlane(sj, j + 4);
            int s5 = __builtin_amdgcn_readlane(sj, j + 5);
            int s6 = __builtin_amdgcn_readlane(sj, j + 6);
            int s7 = __builtin_amdgcn_readlane(sj, j + 7);
            float v0 = bf2f(hb[(size_t)s0 * HD + lane]);
            float v1 = bf2f(hb[(size_t)s1 * HD + lane]);
            float v2 = bf2f(hb[(size_t)s2 * HD + lane]);
            float v3 = bf2f(hb[(size_t)s3 * HD + lane]);
            float v4 = bf2f(hb[(size_t)s4 * HD + lane]);
            float v5 = bf2f(hb[(size_t)s5 * HD + lane]);
            float v6 = bf2f(hb[(size_t)s6 * HD + lane]);
            float v7 = bf2f(hb[(size_t)s7 * HD + lane]);
            acc += ((v0 + v1) + (v2 + v3)) + ((v4 + v5) + (v6 + v7));
        }
        for (; j < m; ++j) {
            int s = __builtin_amdgcn_readlane(sj, j);
            acc += bf2f(hb[(size_t)s * HD + lane]);
        }
    }
    float dn = dinv[wid];
    acc *= dn;
    if (L1) {
        outb[(size_t)wid * HD + lane] = f2bf(fmaxf(acc + bias[lane], 0.f) * dn);
    } else {
        outf[(size_t)wid * HD + lane] = acc;
    }
}

// ---------- GEMM2 + bias: out = agg2 @ W2 + b2 ----------
__global__ __launch_bounds__(256) void k_gemm2(const float* __restrict__ h,
                                               const float* __restrict__ W2,
                                               const float* __restrict__ b2,
                                               float* __restrict__ out) {
    __shared__ float hs[32][65];
    __shared__ float ws2[64][40];
    const int t = threadIdx.x;
    const int r0 = blockIdx.x * 32;
    for (int i = t; i < 64 * OD; i += 256)
        ws2[i / OD][i % OD] = W2[i];
    for (int i = t; i < 32 * 64; i += 256) {
        int r = i >> 6, k = i & 63;
        hs[r][k] = h[(size_t)(r0 + r) * HD + k];
    }
    __syncthreads();
    for (int o = t; o < 32 * OD; o += 256) {
        int r = o / OD, c = o - r * OD;
        float s = 0.f;
        #pragma unroll
        for (int k = 0; k < HD; ++k)
            s = fmaf(hs[r][k], ws2[k][c], s);
        out[(size_t)(r0 + r) * OD + c] = s + b2[c];
    }
}

extern "C" void kernel_launch(void* const* d_in, const int* in_sizes, int n_in,
                              void* d_out, int out_size, void* d_ws, size_t ws_size,
                              hipStream_t stream) {
    const float* x  = (const float*)d_in[0];
    const float* W1 = (const float*)d_in[1];
    const float* b1 = (const float*)d_in[2];
    const float* W2 = (const float*)d_in[3];
    const float* b2 = (const float*)d_in[4];
    const void*  ei = d_in[5];
    float* out = (float*)d_out;

    // --- scratch carved out of d_out (16 MB); all dead before k_gemm2 writes out ---
    char* ob = (char*)d_out;
    int*   rowptr = (int*)ob;                              // 400,004 B
    int*   cnt    = (int*)(ob + 400896);                   // 400,000 B
    int*   bsum   = (int*)(ob + 801280);                   // 1,564 B
    int*   srcs   = (int*)(ob + 803328);                   // 6,400,000 B (end 7,203,328)
    float* dinv   = (float*)(ob + 7203840);                // 400,000 B (end 7,603,840)
    int*   rank   = (int*)(ob + 7604224);                  // 6,400,000 B (end 14,004,224)
    unsigned short* wh = (unsigned short*)(ob + 14004736); // 65,536 B
    unsigned short* wl = (unsigned short*)(ob + 14070272); // 65,536 B (end 14,135,808 < 16 MB)

    // --- ws: feature matrices (bf16 h, fp32 agg2) ---
    char* ws = (char*)d_ws;
    int*            flags  = (int*)ws;                         // 1 KB
    unsigned short* h1b    = (unsigned short*)(ws + 1024);     // 12.8 MB
    unsigned short* hrelub = (unsigned short*)(ws + 1024 + 12800000); // 12.8 MB
    float*          agg2   = (float*)(ws + 1024 + 25600000);   // 25.6 MB (end 51.2 MB)

    k_detect<<<1, 64, 0, stream>>>((const unsigned*)ei, flags);
    k_prepw<<<(KSTEPS * 4 * 64 + 255) / 256, 256, 0, stream>>>(W1, wh, wl);

    // CSR build: count(+rank) -> scan(+dinv) -> scatter (atomic-free)
    hipMemsetAsync(cnt, 0, (size_t)NN * 4, stream);
    k_count<<<(NE / 4 + 255) / 256, 256, 0, stream>>>(ei, flags, cnt, rank);
    k_scan_block<<<NBLK, 256, 0, stream>>>(cnt, rowptr, bsum, dinv);
    k_scan_bsum<<<1, 512, 0, stream>>>(bsum);
    k_scan_add<<<NBLK, 256, 0, stream>>>(rowptr, bsum);
    k_scatter<<<(NE / 4 + 255) / 256, 256, 0, stream>>>(ei, flags, rowptr, rank, srcs);

    // layer 1: MFMA GEMM (split-bf16, LDS-staged, dinv-scaled bf16 output), then CSR agg
    k_gemm1m<<<(NN + 63) / 64, 256, 0, stream>>>(x, (const char*)wh, (const char*)wl, dinv, h1b);
    k_agg<true><<<(NN * 64) / 256, 256, 0, stream>>>(rowptr, srcs, dinv, h1b, b1, hrelub, (float*)nullptr);

    // layer 2: aggregate first (commutes with linear map), then GEMM+bias
    k_agg<false><<<(NN * 64) / 256, 256, 0, stream>>>(rowptr, srcs, dinv, hrelub, (const float*)nullptr, (unsigned short*)nullptr, agg2);
    k_gemm2<<<NN / 32, 256, 0, stream>>>(agg2, W2, b2, out);
}

// Round 8
// 321.278 us; speedup vs baseline: 1.0916x; 1.0109x over previous
//
#include <hip/hip_runtime.h>
#include <cstdint>
#include <cstddef>

#define NN 100000
#define NE 1600000
#define IND 500
#define HD 64
#define OD 40
#define NBLK ((NN + 255) / 256)   // 391 scan blocks
#define KSTEPS 16                 // ceil(500/32)
#define NTT 16                    // k-tiles (BK=32)

typedef __attribute__((ext_vector_type(8))) short short8v;
typedef __attribute__((ext_vector_type(8))) __bf16 bf16x8;
typedef __attribute__((ext_vector_type(4))) float float4v;

// MFMA builtin signature differs across toolchains (short8 vs bf16x8).
template <class V>
static __device__ __forceinline__ auto mfma_bf16_(V a, V b, float4v c, int)
    -> decltype(__builtin_amdgcn_mfma_f32_16x16x32_bf16(a, b, c, 0, 0, 0)) {
    return __builtin_amdgcn_mfma_f32_16x16x32_bf16(a, b, c, 0, 0, 0);
}
template <class V>
static __device__ __forceinline__ float4v mfma_bf16_(V a, V b, float4v c, long) {
    return __builtin_amdgcn_mfma_f32_16x16x32_bf16((bf16x8)a, (bf16x8)b, c, 0, 0, 0);
}
static __device__ __forceinline__ float4v mfma16(short8v a, short8v b, float4v c) {
    return mfma_bf16_(a, b, c, 0);
}

static __device__ __forceinline__ float bf2f(unsigned short v) {
    return __uint_as_float((unsigned)v << 16);
}
static __device__ __forceinline__ unsigned short f2bf(float v) {
    unsigned u = __float_as_uint(v);
    return (unsigned short)((u + 0x7fffu + ((u >> 16) & 1u)) >> 16);
}

// global -> LDS DMA, 16B per lane; dest = wave-uniform base + lane*16
typedef __attribute__((address_space(3))) char lds_char;
typedef const __attribute__((address_space(1))) char g_char;
static __device__ __forceinline__ void gl16(const char* g, char* l) {
    __builtin_amdgcn_global_load_lds((g_char*)g, (lds_char*)l, 16, 0, 0);
}

// load 4 consecutive edge entries starting at element index base (base % 4 == 0)
static __device__ __forceinline__ void load4e(const void* ei, int is64, size_t base, int v[4]) {
    if (is64) {
        int4 a = ((const int4*)ei)[base >> 1];
        int4 b = ((const int4*)ei)[(base >> 1) + 1];
        v[0] = a.x; v[1] = a.z; v[2] = b.x; v[3] = b.z;
    } else {
        int4 a = *(const int4*)((const int*)ei + base);
        v[0] = a.x; v[1] = a.y; v[2] = a.z; v[3] = a.w;
    }
}

// ---------- degree histogram + per-edge rank (atomic return value) ----------
__global__ void k_count(const void* ei, const int* __restrict__ flags, int* cnt,
                        int* __restrict__ rank) {
    int e0 = (blockIdx.x * 256 + threadIdx.x) * 4;
    if (e0 >= NE) return;
    int d[4];
    load4e(ei, flags[0], (size_t)NE + e0, d);
    int4 r;
    r.x = atomicAdd(&cnt[d[0]], 1);
    r.y = atomicAdd(&cnt[d[1]], 1);
    r.z = atomicAdd(&cnt[d[2]], 1);
    r.w = atomicAdd(&cnt[d[3]], 1);
    *(int4*)(rank + e0) = r;
}

// ---------- exclusive scan (3 kernels); dinv fused into pass 1 ----------
__global__ __launch_bounds__(256) void k_scan_block(const int* __restrict__ cnt,
                                                    int* __restrict__ rowptr,
                                                    int* __restrict__ bsum,
                                                    float* __restrict__ dinv) {
    int t = threadIdx.x;
    int i = blockIdx.x * 256 + t;
    int v = (i < NN) ? cnt[i] : 0;
    if (i < NN) dinv[i] = rsqrtf((float)v + 1.0f);   // +1 = self loop
    int inc = v;
    #pragma unroll
    for (int off = 1; off < 64; off <<= 1) {
        int u = __shfl_up(inc, off);
        if ((t & 63) >= off) inc += u;
    }
    __shared__ int wsum[4];
    if ((t & 63) == 63) wsum[t >> 6] = inc;
    __syncthreads();
    if (t == 0) {
        int a = 0;
        #pragma unroll
        for (int w = 0; w < 4; ++w) { int b = wsum[w]; wsum[w] = a; a += b; }
        bsum[blockIdx.x] = a;
    }
    __syncthreads();
    if (i < NN) rowptr[i] = inc - v + wsum[t >> 6];
}

__global__ __launch_bounds__(512) void k_scan_bsum(int* bsum) {
    int t = threadIdx.x;
    int v = (t < NBLK) ? bsum[t] : 0;
    int inc = v;
    #pragma unroll
    for (int off = 1; off < 64; off <<= 1) {
        int u = __shfl_up(inc, off);
        if ((t & 63) >= off) inc += u;
    }
    __shared__ int wsum[8];
    if ((t & 63) == 63) wsum[t >> 6] = inc;
    __syncthreads();
    if (t == 0) {
        int a = 0;
        #pragma unroll
        for (int w = 0; w < 8; ++w) { int b = wsum[w]; wsum[w] = a; a += b; }
    }
    __syncthreads();
    if (t < NBLK) bsum[t] = inc - v + wsum[t >> 6];
}

__global__ void k_scan_add(int* rowptr, const int* __restrict__ bsum) {
    int i = blockIdx.x * 256 + threadIdx.x;
    if (i < NN) rowptr[i] += bsum[i >> 8];
    if (i == 0) rowptr[NN] = NE;
}

// ---------- counting-sort scatter (no atomics: pos = rowptr[d] + rank[e]) ----------
__global__ void k_scatter(const void* ei, const int* __restrict__ flags,
                          const int* __restrict__ rowptr, const int* __restrict__ rank,
                          int* __restrict__ srcs) {
    int e0 = (blockIdx.x * 256 + threadIdx.x) * 4;
    if (e0 >= NE) return;
    int is64 = flags[0];
    int s[4], d[4];
    load4e(ei, is64, (size_t)e0, s);
    load4e(ei, is64, (size_t)NE + e0, d);
    int4 r = *(const int4*)(rank + e0);
    int p0 = rowptr[d[0]] + r.x;
    int p1 = rowptr[d[1]] + r.y;
    int p2 = rowptr[d[2]] + r.z;
    int p3 = rowptr[d[3]] + r.w;
    srcs[p0] = s[0];
    srcs[p1] = s[1];
    srcs[p2] = s[2];
    srcs[p3] = s[3];
}

// ---------- W1 prep: pack into MFMA fragment order, split hi/lo bf16 ----------
// frag index t = (s*4 + f)*64 + lane; lane holds n = f*16+(lane&15), k = s*32+8*(lane>>4)+j
// Also performs the edge int32/int64 detect (block 0, thread 0).
__global__ void k_prepw(const float* __restrict__ W, unsigned short* __restrict__ wh,
                        unsigned short* __restrict__ wl,
                        const unsigned* __restrict__ ei32, int* __restrict__ flags) {
    int t = blockIdx.x * 256 + threadIdx.x;
    if (t == 0) {
        int is64 = 1;
        #pragma unroll
        for (int i = 1; i < 16; i += 2)
            if (ei32[i] != 0u) is64 = 0;
        flags[0] = is64;
    }
    if (t >= KSTEPS * 4 * 64) return;
    int l = t & 63;
    int f = (t >> 6) & 3;
    int s = t >> 8;
    int n = f * 16 + (l & 15);
    int kbase = s * 32 + 8 * (l >> 4);
    unsigned short* ph = wh + (size_t)t * 8;
    unsigned short* pl = wl + (size_t)t * 8;
    #pragma unroll
    for (int j = 0; j < 8; ++j) {
        int k = kbase + j;
        float v = (k < IND) ? W[(size_t)k * HD + n] : 0.f;
        unsigned u = __float_as_uint(v);
        unsigned short hb = (unsigned short)(u >> 16);              // trunc hi
        float r = v - __uint_as_float(u & 0xffff0000u);
        ph[j] = hb;
        pl[j] = f2bf(r);
    }
}

// ---------- GEMM1 (MFMA + global_load_lds staging, BK=32, 5 blocks/CU) ----------
// hs[i] = bf16( dinv[i] * (x @ W1)[i] )
// block = 4 waves = 64 rows; per k-tile: A 8KB (XOR-swizzled source), B 8KB (linear).
static __device__ __forceinline__ void split8f(float4 u0, float4 u1,
                                               short8v& hi, short8v& lo) {
    float t[8] = {u0.x, u0.y, u0.z, u0.w, u1.x, u1.y, u1.z, u1.w};
    #pragma unroll
    for (int j = 0; j < 8; ++j) {
        unsigned q = __float_as_uint(t[j]);
        hi[j] = (short)(q >> 16);
        float r = t[j] - __uint_as_float(q & 0xffff0000u);
        lo[j] = (short)f2bf(r);
    }
}

__global__ __launch_bounds__(256, 5) void k_gemm1m(const float* __restrict__ x,
                                                   const char* __restrict__ whb,
                                                   const char* __restrict__ wlb,
                                                   const float* __restrict__ dinv,
                                                   unsigned short* __restrict__ h) {
    __shared__ char smem[32768];   // 2 bufs x (A 8KB + B 8KB)
    const int tid  = threadIdx.x;
    const int lane = tid & 63;
    const int wave = tid >> 6;
    const int row0 = blockIdx.x * 64;
    const int rA = lane & 15;
    const int cg = lane >> 4;

    // ---- staging: 4x global_load_lds(16B) per thread per k-tile ----
    auto stage = [&](int kt, int buf) {
        const bool tail = (kt == NTT - 1);
        #pragma unroll
        for (int i = 0; i < 2; ++i) {           // A: 512 slots of 16B (64 rows x 8 chunks)
            int slot = i * 256 + tid;
            int r = slot >> 3, c = slot & 7;
            int cs = c ^ (r & 7);               // pre-swizzled source chunk (3-bit bijection)
            if (tail && cs > 4) cs = 4;         // clamp: finite dup data * W-pad(0) = 0
            int rsrc = row0 + r; if (rsrc >= NN) rsrc = NN - 1;
            const char* g = (const char*)x + (size_t)rsrc * (IND * 4) + kt * 128 + cs * 16;
            char* l = smem + buf * 16384 + (i * 256 + wave * 64) * 16;
            gl16(g, l);
        }
        #pragma unroll
        for (int i = 0; i < 2; ++i) {           // B: wh 256 slots + wl 256 slots, linear
            int j = i * 256 + tid;
            const char* src = (j < 256 ? whb : wlb) + kt * 4096 + (size_t)(j & 255) * 16;
            char* l = smem + buf * 16384 + 8192 + (i * 256 + wave * 64) * 16;
            gl16(src, l);
        }
    };

    float4v acc[4];
    const float4v zero4 = {0.f, 0.f, 0.f, 0.f};
    #pragma unroll
    for (int f = 0; f < 4; ++f) acc[f] = zero4;

    stage(0, 0);
    __syncthreads();                            // vmcnt(0) drain + barrier

    int cur = 0;
    const int rbase = (wave * 16 + rA) * 8;     // A row base, in float4 units
    const int sw = rA & 7;

    for (int kt = 0; kt < NTT; ++kt) {
        if (kt + 1 < NTT) stage(kt + 1, cur ^ 1);
        const float4*  pa = (const float4*)(smem + cur * 16384);
        const short8v* pb = (const short8v*)(smem + cur * 16384 + 8192);
        int ch = cg * 2;
        float4 u0 = pa[rbase + (ch ^ sw)];
        float4 u1 = pa[rbase + ((ch + 1) ^ sw)];
        short8v ah, al;
        split8f(u0, u1, ah, al);
        #pragma unroll
        for (int f = 0; f < 4; ++f) {
            short8v vh = pb[f * 64 + lane];
            short8v vl = pb[256 + f * 64 + lane];
            acc[f] = mfma16(al, vh, acc[f]);
            acc[f] = mfma16(ah, vl, acc[f]);
            acc[f] = mfma16(ah, vh, acc[f]);
        }
        __syncthreads();                        // drain stage(kt+1) + barrier
        cur ^= 1;
    }

    // C/D layout (m89-verified): col = lane&15, row = (lane>>4)*4 + reg
    #pragma unroll
    for (int j = 0; j < 4; ++j) {
        int row = row0 + wave * 16 + cg * 4 + j;
        if (row < NN) {
            float dv = dinv[row];
            #pragma unroll
            for (int f = 0; f < 4; ++f)
                h[(size_t)row * HD + f * 16 + rA] = f2bf(acc[f][j] * dv);
        }
    }
}

// ---------- CSR aggregation: out[d] = dn * sum(hs[s]) ; wave per node, lane = channel ----------
template<bool L1>
__global__ __launch_bounds__(256) void k_agg(const int* __restrict__ rowptr,
                                             const int* __restrict__ srcs,
                                             const float* __restrict__ dinv,
                                             const unsigned short* __restrict__ hb,
                                             const float* __restrict__ bias,
                                             unsigned short* __restrict__ outb,
                                             float* __restrict__ outf) {
    int wid = (blockIdx.x * 256 + threadIdx.x) >> 6;
    int lane = threadIdx.x & 63;
    if (wid >= NN) return;
    float acc = bf2f(hb[(size_t)wid * HD + lane]);   // self loop (hs already dinv-scaled)
    int beg = rowptr[wid];
    int cnt = rowptr[wid + 1] - beg;
    for (int base = 0; base < cnt; base += 64) {
        int m = cnt - base; if (m > 64) m = 64;
        int sj = (lane < m) ? srcs[beg + base + lane] : 0;
        int j = 0;
        for (; j + 8 <= m; j += 8) {
            int s0 = __builtin_amdgcn_readlane(sj, j);
            int s1 = __builtin_amdgcn_readlane(sj, j + 1);
            int s2 = __builtin_amdgcn_readlane(sj, j + 2);
            int s3 = __builtin_amdgcn_readlane(sj, j + 3);
            int s4 = __builtin_amdgcn_readlane(sj, j + 4);
            int s5 = __builtin_amdgcn_readlane(sj, j + 5);
            int s6 = __builtin_amdgcn_readlane(sj, j + 6);
            int s7 = __builtin_amdgcn_readlane(sj, j + 7);
            float v0 = bf2f(hb[(size_t)s0 * HD + lane]);
            float v1 = bf2f(hb[(size_t)s1 * HD + lane]);
            float v2 = bf2f(hb[(size_t)s2 * HD + lane]);
            float v3 = bf2f(hb[(size_t)s3 * HD + lane]);
            float v4 = bf2f(hb[(size_t)s4 * HD + lane]);
            float v5 = bf2f(hb[(size_t)s5 * HD + lane]);
            float v6 = bf2f(hb[(size_t)s6 * HD + lane]);
            float v7 = bf2f(hb[(size_t)s7 * HD + lane]);
            acc += ((v0 + v1) + (v2 + v3)) + ((v4 + v5) + (v6 + v7));
        }
        for (; j < m; ++j) {
            int s = __builtin_amdgcn_readlane(sj, j);
            acc += bf2f(hb[(size_t)s * HD + lane]);
        }
    }
    float dn = dinv[wid];
    acc *= dn;
    if (L1) {
        outb[(size_t)wid * HD + lane] = f2bf(fmaxf(acc + bias[lane], 0.f) * dn);
    } else {
        outf[(size_t)wid * HD + lane] = acc;
    }
}

// ---------- GEMM2 + bias: out = agg2 @ W2 + b2 ----------
__global__ __launch_bounds__(256) void k_gemm2(const float* __restrict__ h,
                                               const float* __restrict__ W2,
                                               const float* __restrict__ b2,
                                               float* __restrict__ out) {
    __shared__ float hs[32][65];
    __shared__ float ws2[64][40];
    const int t = threadIdx.x;
    const int r0 = blockIdx.x * 32;
    for (int i = t; i < 64 * OD; i += 256)
        ws2[i / OD][i % OD] = W2[i];
    for (int i = t; i < 32 * 64; i += 256) {
        int r = i >> 6, k = i & 63;
        hs[r][k] = h[(size_t)(r0 + r) * HD + k];
    }
    __syncthreads();
    for (int o = t; o < 32 * OD; o += 256) {
        int r = o / OD, c = o - r * OD;
        float s = 0.f;
        #pragma unroll
        for (int k = 0; k < HD; ++k)
            s = fmaf(hs[r][k], ws2[k][c], s);
        out[(size_t)(r0 + r) * OD + c] = s + b2[c];
    }
}

extern "C" void kernel_launch(void* const* d_in, const int* in_sizes, int n_in,
                              void* d_out, int out_size, void* d_ws, size_t ws_size,
                              hipStream_t stream) {
    const float* x  = (const float*)d_in[0];
    const float* W1 = (const float*)d_in[1];
    const float* b1 = (const float*)d_in[2];
    const float* W2 = (const float*)d_in[3];
    const float* b2 = (const float*)d_in[4];
    const void*  ei = d_in[5];
    float* out = (float*)d_out;

    // --- scratch carved out of d_out (16 MB); all dead before k_gemm2 writes out ---
    char* ob = (char*)d_out;
    int*   rowptr = (int*)ob;                              // 400,004 B
    int*   cnt    = (int*)(ob + 400896);                   // 400,000 B
    int*   bsum   = (int*)(ob + 801280);                   // 1,564 B
    int*   srcs   = (int*)(ob + 803328);                   // 6,400,000 B (end 7,203,328)
    float* dinv   = (float*)(ob + 7203840);                // 400,000 B (end 7,603,840)
    int*   rank   = (int*)(ob + 7604224);                  // 6,400,000 B (end 14,004,224)
    unsigned short* wh = (unsigned short*)(ob + 14004736); // 65,536 B
    unsigned short* wl = (unsigned short*)(ob + 14070272); // 65,536 B (end 14,135,808 < 16 MB)

    // --- ws: feature matrices (bf16 h, fp32 agg2) ---
    char* ws = (char*)d_ws;
    int*            flags  = (int*)ws;                         // 1 KB
    unsigned short* h1b    = (unsigned short*)(ws + 1024);     // 12.8 MB
    unsigned short* hrelub = (unsigned short*)(ws + 1024 + 12800000); // 12.8 MB
    float*          agg2   = (float*)(ws + 1024 + 25600000);   // 25.6 MB (end 51.2 MB)

    // prepw (+ embedded edge dtype detect)
    k_prepw<<<(KSTEPS * 4 * 64 + 255) / 256, 256, 0, stream>>>(W1, wh, wl, (const unsigned*)ei, flags);

    // CSR build: count(+rank) -> scan(+dinv) -> scatter (atomic-free)
    hipMemsetAsync(cnt, 0, (size_t)NN * 4, stream);
    k_count<<<(NE / 4 + 255) / 256, 256, 0, stream>>>(ei, flags, cnt, rank);
    k_scan_block<<<NBLK, 256, 0, stream>>>(cnt, rowptr, bsum, dinv);
    k_scan_bsum<<<1, 512, 0, stream>>>(bsum);
    k_scan_add<<<NBLK, 256, 0, stream>>>(rowptr, bsum);
    k_scatter<<<(NE / 4 + 255) / 256, 256, 0, stream>>>(ei, flags, rowptr, rank, srcs);

    // layer 1: MFMA GEMM (split-bf16, LDS-staged, dinv-scaled bf16 output), then CSR agg
    k_gemm1m<<<(NN + 63) / 64, 256, 0, stream>>>(x, (const char*)wh, (const char*)wl, dinv, h1b);
    k_agg<true><<<(NN * 64) / 256, 256, 0, stream>>>(rowptr, srcs, dinv, h1b, b1, hrelub, (float*)nullptr);

    // layer 2: aggregate first (commutes with linear map), then GEMM+bias
    k_agg<false><<<(NN * 64) / 256, 256, 0, stream>>>(rowptr, srcs, dinv, hrelub, (const float*)nullptr, (unsigned short*)nullptr, agg2);
    k_gemm2<<<NN / 32, 256, 0, stream>>>(agg2, W2, b2, out);
}